// Round 10
// baseline (1725.539 us; speedup 1.0000x reference)
//
#include <hip/hip_runtime.h>
#include <hip/hip_bf16.h>
#include <hip/hip_fp16.h>

typedef short bf16x8 __attribute__((ext_vector_type(8)));
typedef float f32x4 __attribute__((ext_vector_type(4)));
typedef unsigned short u16x4 __attribute__((ext_vector_type(4)));
typedef unsigned int uint32;

#define MFMA_B16(a,b,c) __builtin_amdgcn_mfma_f32_16x16x32_bf16(a,b,c,0,0,0)

// ---------------- geometry ----------------
#define NS   1024
#define TLEN 128
#define DD   343
#define HH   150
#define GG   600
#define KX   352    // padded DD
#define KXP  44
#define NP   640    // gate-major padded dim: n' = gate*160 + j, j<160
#define NG2  640    // XG2 row width (gate-major)

// ---------------- ws layout (bytes) ----------------
#define OFF_WXP  0u          // bf16 [2][44][640][8]   901120
#define OFF_WHP  901120u     // bf16 [2][20][640][8]   409600
#define OFF_B1   1310720u    // f32  [2][640]          5120
#define OFF_W2B  1315840u    // bf16 [2][640][160]     409600
#define OFF_W2I  1725440u    // f32  [2][300][608]     1459200
#define OFF_SE   3184640u    // f32  [1024][300]       1228800
#define OFF_XG2  4413440u    // f32  [2][1024][640]    5242880
#define OFF_H2O  9656320u    // f32  [1024][300]       1228800
#define OFF_XBF  10885120u   // bf16 [1024][128][352]  92274688
#define NEED_BF  103159808ull

// prep section boundaries (element counts)
#define PE0 450560            // WXp
#define PE1 655360            // + WHp 204800
#define PE2 656640            // + B1 1280
#define PE3 861440            // + W2B 204800
#define PE4 1226240           // + W2I 364800

__device__ __forceinline__ float rcp_fast(float x) { return __builtin_amdgcn_rcpf(x); }
__device__ __forceinline__ float sigm(float x) { return rcp_fast(1.f + __expf(-x)); }
__device__ __forceinline__ float tanh_fast(float x) { return 1.f - 2.f * rcp_fast(__expf(2.f * x) + 1.f); }

typedef __attribute__((address_space(1))) const void GASV;
typedef __attribute__((address_space(3))) void LASV;
__device__ __forceinline__ void gload_lds16(const void* g, void* l) {
  __builtin_amdgcn_global_load_lds((GASV*)g, (LASV*)l, 16, 0, 0);
}

__device__ __forceinline__ void bar_lds() {
  asm volatile("s_waitcnt lgkmcnt(0)" ::: "memory");
  __builtin_amdgcn_s_barrier();
  asm volatile("" ::: "memory");
}
__device__ __forceinline__ void bar_full() {
  asm volatile("s_waitcnt vmcnt(0) lgkmcnt(0)" ::: "memory");
  __builtin_amdgcn_s_barrier();
  asm volatile("" ::: "memory");
}

__device__ __forceinline__ unsigned short f2bu(float v) {
  __hip_bfloat16 b = __float2bfloat16(v);
  return __builtin_bit_cast(unsigned short, b);
}

// ---------------- prep: pack weights gate-major (n' = g*160 + j) ----------------
__global__ __launch_bounds__(256) void prep_kernel(
    const float* __restrict__ wif1, const float* __restrict__ whf1,
    const float* __restrict__ bif1, const float* __restrict__ bhf1,
    const float* __restrict__ wib1, const float* __restrict__ whb1,
    const float* __restrict__ bib1, const float* __restrict__ bhb1,
    const float* __restrict__ wif2, const float* __restrict__ wib2,
    const float* __restrict__ whf2, const float* __restrict__ whb2,
    __hip_bfloat16* __restrict__ WXp, __hip_bfloat16* __restrict__ WHp,
    float* __restrict__ B1, __hip_bfloat16* __restrict__ W2B, float* __restrict__ W2I)
{
  int i = blockIdx.x * 256 + threadIdx.x;
  if (i < PE0) {
    int d = i / 225280; int r = i - d * 225280;
    int p = r / 5120;   int r2 = r - p * 5120;
    int n2 = r2 >> 3;   int jj = r2 & 7;
    int k = p * 8 + jj;
    int g = n2 / 160, j = n2 - g * 160;
    const float* w = d ? wib1 : wif1;
    float v = (j < HH && k < DD) ? w[(g * HH + j) * DD + k] : 0.f;
    WXp[i] = __float2bfloat16(v);
  } else if (i < PE1) {
    int ii = i - PE0;
    int d = ii / 102400; int r = ii - d * 102400;
    int p = r / 5120;    int r2 = r - p * 5120;
    int n2 = r2 >> 3;    int jj = r2 & 7;
    int k = p * 8 + jj;
    int g = n2 / 160, j = n2 - g * 160;
    const float* w = d ? whb1 : whf1;
    float v = (j < HH && k < HH) ? w[(g * HH + j) * HH + k] : 0.f;
    WHp[ii] = __float2bfloat16(v);
  } else if (i < PE2) {
    int ii = i - PE1;
    int d = ii / NP; int n2 = ii - d * NP;
    int g = n2 / 160, j = n2 - g * 160;
    float v = 0.f;
    if (j < HH) {
      int n = g * HH + j;
      v = d ? (bib1[n] + bhb1[n]) : (bif1[n] + bhf1[n]);
    }
    B1[ii] = v;
  } else if (i < PE3) {
    int ii = i - PE2;
    int d = ii / 102400; int r = ii - d * 102400;
    int n2 = r / 160;    int k = r - n2 * 160;
    int g = n2 / 160, j = n2 - g * 160;
    const float* w = d ? whb2 : whf2;
    float v = (j < HH && k < HH) ? w[(g * HH + j) * HH + k] : 0.f;
    W2B[ii] = __float2bfloat16(v);
  } else if (i < PE4) {
    int ii = i - PE3;
    int d = ii / 182400; int r = ii - d * 182400;
    int k = r / 608;     int n = r - k * 608;
    const float* w = d ? wib2 : wif2;
    float v = (n < GG) ? w[n * 300 + k] : 0.f;
    W2I[ii] = v;
  }
}

// ---------------- x -> bf16 padded [S][T][352] ----------------
__global__ __launch_bounds__(256) void xcvt_kernel(
    const float* __restrict__ x, __hip_bfloat16* __restrict__ XBF)
{
  const int total4 = NS * TLEN * (KX / 4);
  for (int idx = blockIdx.x * 256 + threadIdx.x; idx < total4; idx += gridDim.x * 256) {
    int row = idx / 88;
    int c4 = (idx - row * 88) * 4;
    const float* src = x + (size_t)row * DD + c4;
    float v0 = 0.f, v1 = 0.f, v2 = 0.f, v3 = 0.f;
    if (c4 + 3 < DD) {
      v0 = __builtin_nontemporal_load(src);
      v1 = __builtin_nontemporal_load(src + 1);
      v2 = __builtin_nontemporal_load(src + 2);
      v3 = __builtin_nontemporal_load(src + 3);
    } else {
      if (c4 < DD)     v0 = src[0];
      if (c4 + 1 < DD) v1 = src[1];
      if (c4 + 2 < DD) v2 = src[2];
    }
    u16x4 o;
    o.x = f2bu(v0); o.y = f2bu(v1); o.z = f2bu(v2); o.w = f2bu(v3);
    u16x4* dst = (u16x4*)((unsigned short*)XBF + (size_t)row * KX + c4);
    __builtin_nontemporal_store(o, dst);
  }
}

// ---------------- layer-1: gate-major, in-register cell ----------------
// 256 blocks = 128 groups(8 sents) x 2 dirs, 640 threads (10 waves).
// Wave wv owns the {i,f,g,o} gate-quad of j-tile wv (j = wv*16 + c16).
// TB=4 steps per g: 2 pairs; rows 0-7 = even step sents, 8-15 = odd step.
// D mapping: thread (c16,kgrp) holds rows kgrp*4+r -> all 4 gates of (s,j)
// in acc[p][gate][r]. Cell fully in registers; c-state crosses even/odd
// lane groups via shfl_xor(.,32); only h (bf16) goes through LDS.
#define XS_SZ   22528u                    // bf16 [2p][16][352]
#define HS_OFF  (2u * XS_SZ)              // bf16 [16][160] = 5120
#define L1_SMEM (HS_OFF + 5120u)          // 50176 real
#define L1_SMEM_REQ 102400u               // padded: force 1 block/CU

template<bool BF>
__device__ __forceinline__ void stage_x(char* xsd, const float* __restrict__ x,
                                        const __hip_bfloat16* __restrict__ XBF,
                                        int t0, int dir, int s0, int tid, int lane, int wv)
{
  if constexpr (BF) {
    #pragma unroll
    for (int i = 0; i < 3; ++i) {
      int id = i * 10 + wv;
      if (id < 22) {
        int chunk = id * 64 + lane;
        int row16 = chunk / 44;
        int col16 = chunk - row16 * 44;
        int p = row16 >> 4, rr = row16 & 15;
        int t = t0 + 2 * p + (rr >> 3);
        int s = s0 + (rr & 7);
        int tt = dir ? (127 - t) : t;
        const __hip_bfloat16* gp = XBF + ((size_t)s * TLEN + tt) * KX + col16 * 8;
        gload_lds16((const void*)gp, (void*)(xsd + id * 1024));
      }
    }
  } else {
    for (int e = tid; e < 2 * 16 * KX; e += 640) {
      int row16 = e / KX;
      int col = e - row16 * KX;
      int p = row16 >> 4, rr = row16 & 15;
      int t = t0 + 2 * p + (rr >> 3);
      int s = s0 + (rr & 7);
      int tt = dir ? (127 - t) : t;
      float v = (col < DD) ? x[((size_t)s * TLEN + tt) * DD + col] : 0.f;
      ((__hip_bfloat16*)xsd)[e] = __float2bfloat16(v);
    }
  }
}

template<bool BF>
__global__ __launch_bounds__(640)
void lstm1_kernel(
    const float* __restrict__ x, const __hip_bfloat16* __restrict__ XBF,
    const __hip_bfloat16* __restrict__ WXp, const __hip_bfloat16* __restrict__ WHp,
    const float* __restrict__ B1, float* __restrict__ SE)
{
  extern __shared__ char smem[];
  char* xs0 = smem;
  char* xs1 = smem + XS_SZ;
  __hip_bfloat16* hs = (__hip_bfloat16*)(smem + HS_OFF);

  const int tid = threadIdx.x;
  const int lane = tid & 63;
  const int wv = tid >> 6;            // 0..9 = j-tile
  const int dir = blockIdx.x & 1;
  const int s0 = (blockIdx.x >> 1) * 8;
  const int c16 = lane & 15;
  const int kgrp = lane >> 4;
  const int j = wv * 16 + c16;        // 0..159

  for (int e = tid; e < 16 * 160; e += 640) hs[e] = __float2bfloat16(0.f);

  float bias[4];
  #pragma unroll
  for (int g4 = 0; g4 < 4; ++g4) {
    bias[g4] = B1[dir * NP + g4 * 160 + j];
    asm volatile("" : "+v"(bias[g4]));
  }

  const __hip_bfloat16* WXd = WXp + (size_t)dir * KXP * NP * 8;
  const __hip_bfloat16* WHd = WHp + (size_t)dir * 20 * NP * 8;

  bf16x8 whr[5][4];
  #pragma unroll
  for (int kh = 0; kh < 5; ++kh)
    #pragma unroll
    for (int g4 = 0; g4 < 4; ++g4) {
      whr[kh][g4] = *reinterpret_cast<const bf16x8*>(
          WHd + ((size_t)(kh * 4 + kgrp) * NP + g4 * 160 + j) * 8);
      asm volatile("" : "+v"(whr[kh][g4]));
    }

  float creg[4] = {0.f, 0.f, 0.f, 0.f};
  float mxr[4] = {-3e38f, -3e38f, -3e38f, -3e38f};

  stage_x<BF>(xs0, x, XBF, 0, dir, s0, tid, lane, wv);
  bar_full();

  for (int g = 0; g < 32; ++g) {
    char* xsc = (g & 1) ? xs1 : xs0;
    char* xsn = (g & 1) ? xs0 : xs1;
    const __hip_bfloat16* xsb = (const __hip_bfloat16*)xsc;

    f32x4 acc[2][4];
    #pragma unroll
    for (int p = 0; p < 2; ++p)
      #pragma unroll
      for (int g4 = 0; g4 < 4; ++g4) acc[p][g4] = (f32x4){0.f, 0.f, 0.f, 0.f};

    // ---- phase A: x-projection for 4 steps (2 row-paired tiles) ----
    for (int kk = 0; kk < 11; ++kk) {
      bf16x8 a[2], b[4];
      #pragma unroll
      for (int p = 0; p < 2; ++p)
        a[p] = *reinterpret_cast<const bf16x8*>(xsb + (p * 16 + c16) * KX + kk * 32 + kgrp * 8);
      #pragma unroll
      for (int g4 = 0; g4 < 4; ++g4)
        b[g4] = *reinterpret_cast<const bf16x8*>(
            WXd + ((size_t)(kk * 4 + kgrp) * NP + g4 * 160 + j) * 8);
      #pragma unroll
      for (int p = 0; p < 2; ++p)
        #pragma unroll
        for (int g4 = 0; g4 < 4; ++g4)
          acc[p][g4] = MFMA_B16(a[p], b[g4], acc[p][g4]);
    }

    if (g < 31)
      stage_x<BF>(xsn, x, XBF, (g + 1) * 4, dir, s0, tid, lane, wv);

    // ---- phase B: 2 pairs = 4 recurrent steps ----
    #pragma unroll
    for (int p = 0; p < 2; ++p) {
      // MFMA1: rows 0-7 += h_prev_odd * Wh  (rows 8-15 see zeros)
      #pragma unroll
      for (int kh = 0; kh < 5; ++kh) {
        bf16x8 ah = *reinterpret_cast<const bf16x8*>(hs + c16 * 160 + kh * 32 + kgrp * 8);
        #pragma unroll
        for (int g4 = 0; g4 < 4; ++g4)
          acc[p][g4] = MFMA_B16(ah, whr[kh][g4], acc[p][g4]);
      }
      // even-step cell: valid in kgrp<2 lanes (rows 0-7)
      {
        const bool act = (kgrp < 2);
        #pragma unroll
        for (int r = 0; r < 4; ++r) {
          float iv = sigm(acc[p][0][r] + bias[0]);
          float fv = sigm(acc[p][1][r] + bias[1]);
          float gv = tanh_fast(acc[p][2][r] + bias[2]);
          float ov = sigm(acc[p][3][r] + bias[3]);
          float cin = __shfl_xor(creg[r], 32);
          float cn = fv * cin + iv * gv;
          float h = ov * tanh_fast(cn);
          creg[r] = act ? cn : creg[r];
          mxr[r] = act ? fmaxf(mxr[r], h) : mxr[r];
          if (act) hs[(8 + kgrp * 4 + r) * 160 + j] = __float2bfloat16(h);
        }
      }
      bar_lds();
      // MFMA2: rows 8-15 += h_even * Wh (rows 0-7 dead)
      #pragma unroll
      for (int kh = 0; kh < 5; ++kh) {
        bf16x8 ah = *reinterpret_cast<const bf16x8*>(hs + c16 * 160 + kh * 32 + kgrp * 8);
        #pragma unroll
        for (int g4 = 0; g4 < 4; ++g4)
          acc[p][g4] = MFMA_B16(ah, whr[kh][g4], acc[p][g4]);
      }
      // odd-step cell: valid in kgrp>=2 lanes (rows 8-15)
      {
        const bool act = (kgrp >= 2);
        #pragma unroll
        for (int r = 0; r < 4; ++r) {
          float iv = sigm(acc[p][0][r] + bias[0]);
          float fv = sigm(acc[p][1][r] + bias[1]);
          float gv = tanh_fast(acc[p][2][r] + bias[2]);
          float ov = sigm(acc[p][3][r] + bias[3]);
          float cin = __shfl_xor(creg[r], 32);
          float cn = fv * cin + iv * gv;
          float h = ov * tanh_fast(cn);
          creg[r] = act ? cn : creg[r];
          mxr[r] = act ? fmaxf(mxr[r], h) : mxr[r];
          if (act) {
            int s = (kgrp - 2) * 4 + r;
            hs[s * 160 + j] = __float2bfloat16(h);
            hs[(8 + s) * 160 + j] = __float2bfloat16(0.f);
          }
        }
      }
      if (p == 1) bar_full(); else bar_lds();
    }
  }

  // SE: merge even/odd running max via shfl, write by kgrp<2 lanes
  #pragma unroll
  for (int r = 0; r < 4; ++r) {
    float m = fmaxf(mxr[r], __shfl_xor(mxr[r], 32));
    if (kgrp < 2 && j < HH)
      SE[(size_t)(s0 + kgrp * 4 + r) * 300 + dir * HH + j] = m;
  }
}

// ---------------- layer-2 input projection (gate-major output, zero pad) ----------------
__global__ __launch_bounds__(256, 1) void xg2_kernel(
    const float* __restrict__ SE, const float* __restrict__ W2I,
    const float* __restrict__ bif2, const float* __restrict__ bhf2,
    const float* __restrict__ bib2, const float* __restrict__ bhb2,
    float* __restrict__ XG2)
{
  __shared__ float se[32 * 304];
  const int d = blockIdx.x >> 5, st = blockIdx.x & 31, sb = st * 32;
  const int tid = threadIdx.x;
  for (int e = tid; e < 32 * 300; e += 256) {
    int si = e / 300, k = e - si * 300;
    se[si * 304 + k] = SE[(size_t)(sb + si) * 300 + k];
  }
  __syncthreads();
  for (int pass = 0; pass < 3; ++pass) {
    int n = pass * 256 + tid;
    if (n < GG) {
      int n2 = (n / 150) * 160 + (n % 150);
      float bias = d ? (bib2[n] + bhb2[n]) : (bif2[n] + bhf2[n]);
      float acc[32];
      #pragma unroll
      for (int si = 0; si < 32; ++si) acc[si] = bias;
      const float* wcol = W2I + (size_t)d * 300 * 608 + n;
      for (int k = 0; k < 300; ++k) {
        float wvv = wcol[(size_t)k * 608];
        #pragma unroll
        for (int si = 0; si < 32; ++si) acc[si] += wvv * se[si * 304 + k];
      }
      #pragma unroll
      for (int si = 0; si < 32; ++si)
        XG2[((size_t)d * NS + sb + si) * NG2 + n2] = acc[si];
    }
  }
  // zero the pad columns (j in [150,160) per gate)
  for (int e = tid; e < 32 * 40; e += 256) {
    int si = e / 40, q = e - si * 40;
    int g = q / 10, jp = 150 + (q - g * 10);
    XG2[((size_t)d * NS + sb + si) * NG2 + g * 160 + jp] = 0.f;
  }
}

// ---------------- layer-2 recurrence: gate-major MFMA, in-register cell ----------------
// Wave wv owns j-tile wv (j = wv*16+c16), 4 gate-tiles -> thread holds all 4
// gates of its j -> cell in registers (kg-redundant). h double-buffered in LDS
// -> ONE barrier per step. MFMA chains split 3+2.
__global__ __launch_bounds__(640) void lstm2_kernel(
    const __hip_bfloat16* __restrict__ W2B, const float* __restrict__ XG2,
    float* __restrict__ H2O)
{
  const int dir = blockIdx.x;
  const int tid = threadIdx.x;
  const int lane = tid & 63;
  const int wv = tid >> 6;        // 0..9 = j-tile
  const int c16 = lane & 15;
  const int kg = lane >> 4;
  const int j = wv * 16 + c16;    // 0..159
  __shared__ __align__(16) __hip_bfloat16 hbuf[2][160];

  const f32x4 ZERO4 = {0.f, 0.f, 0.f, 0.f};

  const __hip_bfloat16* Wd = W2B + (size_t)dir * NP * 160;
  bf16x8 wf[5][4];
  #pragma unroll
  for (int kt = 0; kt < 5; ++kt)
    #pragma unroll
    for (int g4 = 0; g4 < 4; ++g4) {
      wf[kt][g4] = *reinterpret_cast<const bf16x8*>(
          Wd + (size_t)(g4 * 160 + j) * 160 + kt * 32 + kg * 8);
      asm volatile("" : "+v"(wf[kt][g4]));
    }

  if (tid < 160) hbuf[0][tid] = __float2bfloat16(0.f);
  __syncthreads();

  float creg = 0.f;
  const float* xg = XG2 + (size_t)dir * NS * NG2;
  float xv[4];
  {
    int ss0 = dir ? 1023 : 0;
    #pragma unroll
    for (int g4 = 0; g4 < 4; ++g4) xv[g4] = xg[(size_t)ss0 * NG2 + g4 * 160 + j];
  }

  for (int step = 0; step < 1024; ++step) {
    const int ss = dir ? (1023 - step) : step;
    float xn[4] = {0.f, 0.f, 0.f, 0.f};
    if (step < 1023) {
      int ss2 = dir ? (1022 - step) : (step + 1);
      #pragma unroll
      for (int g4 = 0; g4 < 4; ++g4) xn[g4] = xg[(size_t)ss2 * NG2 + g4 * 160 + j];
    }
    const int cur = step & 1;
    bf16x8 hf[5];
    #pragma unroll
    for (int kt = 0; kt < 5; ++kt)
      hf[kt] = *reinterpret_cast<const bf16x8*>(&hbuf[cur][kt * 32 + kg * 8]);
    f32x4 aA[4], aB[4];
    #pragma unroll
    for (int g4 = 0; g4 < 4; ++g4) {
      aA[g4] = MFMA_B16(hf[0], wf[0][g4], ZERO4);
      aB[g4] = MFMA_B16(hf[1], wf[1][g4], ZERO4);
    }
    #pragma unroll
    for (int g4 = 0; g4 < 4; ++g4) {
      aA[g4] = MFMA_B16(hf[2], wf[2][g4], aA[g4]);
      aB[g4] = MFMA_B16(hf[3], wf[3][g4], aB[g4]);
      aA[g4] = MFMA_B16(hf[4], wf[4][g4], aA[g4]);
    }
    float iv = sigm(aA[0][0] + aB[0][0] + xv[0]);
    float fv = sigm(aA[1][0] + aB[1][0] + xv[1]);
    float gv = tanh_fast(aA[2][0] + aB[2][0] + xv[2]);
    float ov = sigm(aA[3][0] + aB[3][0] + xv[3]);
    creg = fv * creg + iv * gv;
    float nh = ov * tanh_fast(creg);
    if (kg == 0) {
      hbuf[cur ^ 1][j] = __float2bfloat16(nh);
      if (j < HH) H2O[(size_t)ss * 300 + dir * HH + j] = nh;
    }
    bar_lds();
    #pragma unroll
    for (int g4 = 0; g4 < 4; ++g4) xv[g4] = xn[g4];
  }
}

// ---------------- head ----------------
__global__ __launch_bounds__(256, 1) void head_kernel(
    const float* __restrict__ H2O, const float* __restrict__ w_out,
    const float* __restrict__ b_out, float* __restrict__ out)
{
  int s = blockIdx.x * 256 + threadIdx.x;
  if (s >= NS) return;
  float acc[7];
  #pragma unroll
  for (int c = 0; c < 7; ++c) acc[c] = b_out[c];
  const float* hrow = H2O + (size_t)s * 300;
  for (int k = 0; k < 300; ++k) {
    float hv = hrow[k];
    #pragma unroll
    for (int c = 0; c < 7; ++c) acc[c] += hv * w_out[c * 300 + k];
  }
  float m = acc[0];
  #pragma unroll
  for (int c = 1; c < 7; ++c) m = fmaxf(m, acc[c]);
  float sum = 0.f;
  #pragma unroll
  for (int c = 0; c < 7; ++c) sum += __expf(acc[c] - m);
  float lse = m + __logf(sum);
  #pragma unroll
  for (int c = 0; c < 7; ++c) out[s * 7 + c] = acc[c] - lse;
}

extern "C" void kernel_launch(void* const* d_in, const int* in_sizes, int n_in,
                              void* d_out, int out_size, void* d_ws, size_t ws_size,
                              hipStream_t stream) {
  const float* x      = (const float*)d_in[0];
  const float* wif1   = (const float*)d_in[1];
  const float* whf1   = (const float*)d_in[2];
  const float* bif1   = (const float*)d_in[3];
  const float* bhf1   = (const float*)d_in[4];
  const float* wib1   = (const float*)d_in[5];
  const float* whb1   = (const float*)d_in[6];
  const float* bib1   = (const float*)d_in[7];
  const float* bhb1   = (const float*)d_in[8];
  const float* wif2   = (const float*)d_in[9];
  const float* whf2   = (const float*)d_in[10];
  const float* bif2   = (const float*)d_in[11];
  const float* bhf2   = (const float*)d_in[12];
  const float* wib2   = (const float*)d_in[13];
  const float* whb2   = (const float*)d_in[14];
  const float* bib2   = (const float*)d_in[15];
  const float* bhb2   = (const float*)d_in[16];
  const float* w_out  = (const float*)d_in[17];
  const float* b_out  = (const float*)d_in[18];

  char* ws = (char*)d_ws;
  __hip_bfloat16* WXp = (__hip_bfloat16*)(ws + OFF_WXP);
  __hip_bfloat16* WHp = (__hip_bfloat16*)(ws + OFF_WHP);
  float*    B1  = (float*)(ws + OFF_B1);
  __hip_bfloat16* W2B = (__hip_bfloat16*)(ws + OFF_W2B);
  float*    W2I = (float*)(ws + OFF_W2I);
  float*    SE  = (float*)(ws + OFF_SE);
  float*    XG2 = (float*)(ws + OFF_XG2);
  float*    H2O = (float*)(ws + OFF_H2O);
  __hip_bfloat16* XBF = (__hip_bfloat16*)(ws + OFF_XBF);

  const bool useBF = (ws_size >= NEED_BF);

  prep_kernel<<<(PE4 + 255) / 256, 256, 0, stream>>>(
      wif1, whf1, bif1, bhf1, wib1, whb1, bib1, bhb1,
      wif2, wib2, whf2, whb2, WXp, WHp, B1, W2B, W2I);

  if (useBF)
    xcvt_kernel<<<4096, 256, 0, stream>>>(x, XBF);

  (void)hipFuncSetAttribute((const void*)(lstm1_kernel<true>),
                            hipFuncAttributeMaxDynamicSharedMemorySize, L1_SMEM_REQ);
  (void)hipFuncSetAttribute((const void*)(lstm1_kernel<false>),
                            hipFuncAttributeMaxDynamicSharedMemorySize, L1_SMEM_REQ);

  if (useBF)
    lstm1_kernel<true><<<256, 640, L1_SMEM_REQ, stream>>>(x, XBF, WXp, WHp, B1, SE);
  else
    lstm1_kernel<false><<<256, 640, L1_SMEM_REQ, stream>>>(x, XBF, WXp, WHp, B1, SE);

  xg2_kernel<<<64, 256, 0, stream>>>(SE, W2I, bif2, bhf2, bib2, bhb2, XG2);

  lstm2_kernel<<<2, 640, 0, stream>>>(W2B, XG2, H2O);

  head_kernel<<<4, 256, 0, stream>>>(H2O, w_out, b_out, (float*)d_out);
}

// Round 11
// 1718.608 us; speedup vs baseline: 1.0040x; 1.0040x over previous
//
#include <hip/hip_runtime.h>
#include <hip/hip_bf16.h>
#include <hip/hip_fp16.h>

typedef short bf16x8 __attribute__((ext_vector_type(8)));
typedef float f32x4 __attribute__((ext_vector_type(4)));
typedef unsigned short u16x4 __attribute__((ext_vector_type(4)));
typedef unsigned int uint32;

#define MFMA_B16(a,b,c) __builtin_amdgcn_mfma_f32_16x16x32_bf16(a,b,c,0,0,0)

// ---------------- geometry ----------------
#define NS   1024
#define TLEN 128
#define DD   343
#define HH   150
#define GG   600
#define KX   352    // XBF row width (global)
#define XR   360    // xs LDS row width (720B = 45x16B odd -> conflict-free)
#define HR   168    // hs LDS row width (336B = 21x16B odd -> conflict-free)
#define KXP  44
#define NP   640    // gate-major padded dim: n' = gate*160 + j, j<160
#define NG2  640    // XG2 row width (gate-major)

// ---------------- ws layout (bytes) ----------------
#define OFF_WXP  0u          // bf16 [2][44][640][8]   901120
#define OFF_WHP  901120u     // bf16 [2][20][640][8]   409600
#define OFF_B1   1310720u    // f32  [2][640]          5120
#define OFF_W2B  1315840u    // bf16 [2][640][160]     409600
#define OFF_W2I  1725440u    // f32  [2][300][608]     1459200
#define OFF_SE   3184640u    // f32  [1024][300]       1228800
#define OFF_XG2  4413440u    // f32  [2][1024][640]    5242880
#define OFF_H2O  9656320u    // f32  [1024][300]       1228800
#define OFF_XBF  10885120u   // bf16 [1024][128][352]  92274688
#define NEED_BF  103159808ull

// prep section boundaries (element counts)
#define PE0 450560            // WXp
#define PE1 655360            // + WHp 204800
#define PE2 656640            // + B1 1280
#define PE3 861440            // + W2B 204800
#define PE4 1226240           // + W2I 364800

__device__ __forceinline__ float rcp_fast(float x) { return __builtin_amdgcn_rcpf(x); }
__device__ __forceinline__ float sigm(float x) { return rcp_fast(1.f + __expf(-x)); }
__device__ __forceinline__ float tanh_fast(float x) { return 1.f - 2.f * rcp_fast(__expf(2.f * x) + 1.f); }

typedef __attribute__((address_space(1))) const void GASV;
typedef __attribute__((address_space(3))) void LASV;
__device__ __forceinline__ void gload_lds16(const void* g, void* l) {
  __builtin_amdgcn_global_load_lds((GASV*)g, (LASV*)l, 16, 0, 0);
}
// NT (non-temporal) variant: aux=2 sets the NT CPol bit on gfx94x/gfx950.
// XBF is streamed once -> keep it from evicting L2-resident weights.
__device__ __forceinline__ void gload_lds16_nt(const void* g, void* l) {
  __builtin_amdgcn_global_load_lds((GASV*)g, (LASV*)l, 16, 0, 2);
}

__device__ __forceinline__ void bar_lds() {
  asm volatile("s_waitcnt lgkmcnt(0)" ::: "memory");
  __builtin_amdgcn_s_barrier();
  asm volatile("" ::: "memory");
}
__device__ __forceinline__ void bar_full() {
  asm volatile("s_waitcnt vmcnt(0) lgkmcnt(0)" ::: "memory");
  __builtin_amdgcn_s_barrier();
  asm volatile("" ::: "memory");
}

__device__ __forceinline__ unsigned short f2bu(float v) {
  __hip_bfloat16 b = __float2bfloat16(v);
  return __builtin_bit_cast(unsigned short, b);
}

// ---------------- prep: pack weights gate-major (n' = g*160 + j) ----------------
__global__ __launch_bounds__(256) void prep_kernel(
    const float* __restrict__ wif1, const float* __restrict__ whf1,
    const float* __restrict__ bif1, const float* __restrict__ bhf1,
    const float* __restrict__ wib1, const float* __restrict__ whb1,
    const float* __restrict__ bib1, const float* __restrict__ bhb1,
    const float* __restrict__ wif2, const float* __restrict__ wib2,
    const float* __restrict__ whf2, const float* __restrict__ whb2,
    __hip_bfloat16* __restrict__ WXp, __hip_bfloat16* __restrict__ WHp,
    float* __restrict__ B1, __hip_bfloat16* __restrict__ W2B, float* __restrict__ W2I)
{
  int i = blockIdx.x * 256 + threadIdx.x;
  if (i < PE0) {
    int d = i / 225280; int r = i - d * 225280;
    int p = r / 5120;   int r2 = r - p * 5120;
    int n2 = r2 >> 3;   int jj = r2 & 7;
    int k = p * 8 + jj;
    int g = n2 / 160, j = n2 - g * 160;
    const float* w = d ? wib1 : wif1;
    float v = (j < HH && k < DD) ? w[(g * HH + j) * DD + k] : 0.f;
    WXp[i] = __float2bfloat16(v);
  } else if (i < PE1) {
    int ii = i - PE0;
    int d = ii / 102400; int r = ii - d * 102400;
    int p = r / 5120;    int r2 = r - p * 5120;
    int n2 = r2 >> 3;    int jj = r2 & 7;
    int k = p * 8 + jj;
    int g = n2 / 160, j = n2 - g * 160;
    const float* w = d ? whb1 : whf1;
    float v = (j < HH && k < HH) ? w[(g * HH + j) * HH + k] : 0.f;
    WHp[ii] = __float2bfloat16(v);
  } else if (i < PE2) {
    int ii = i - PE1;
    int d = ii / NP; int n2 = ii - d * NP;
    int g = n2 / 160, j = n2 - g * 160;
    float v = 0.f;
    if (j < HH) {
      int n = g * HH + j;
      v = d ? (bib1[n] + bhb1[n]) : (bif1[n] + bhf1[n]);
    }
    B1[ii] = v;
  } else if (i < PE3) {
    int ii = i - PE2;
    int d = ii / 102400; int r = ii - d * 102400;
    int n2 = r / 160;    int k = r - n2 * 160;
    int g = n2 / 160, j = n2 - g * 160;
    const float* w = d ? whb2 : whf2;
    float v = (j < HH && k < HH) ? w[(g * HH + j) * HH + k] : 0.f;
    W2B[ii] = __float2bfloat16(v);
  } else if (i < PE4) {
    int ii = i - PE3;
    int d = ii / 182400; int r = ii - d * 182400;
    int k = r / 608;     int n = r - k * 608;
    const float* w = d ? wib2 : wif2;
    float v = (n < GG) ? w[n * 300 + k] : 0.f;
    W2I[ii] = v;
  }
}

// ---------------- x -> bf16 padded [S][T][352] ----------------
__global__ __launch_bounds__(256) void xcvt_kernel(
    const float* __restrict__ x, __hip_bfloat16* __restrict__ XBF)
{
  const int total4 = NS * TLEN * (KX / 4);
  for (int idx = blockIdx.x * 256 + threadIdx.x; idx < total4; idx += gridDim.x * 256) {
    int row = idx / 88;
    int c4 = (idx - row * 88) * 4;
    const float* src = x + (size_t)row * DD + c4;
    float v0 = 0.f, v1 = 0.f, v2 = 0.f, v3 = 0.f;
    if (c4 + 3 < DD) {
      v0 = __builtin_nontemporal_load(src);
      v1 = __builtin_nontemporal_load(src + 1);
      v2 = __builtin_nontemporal_load(src + 2);
      v3 = __builtin_nontemporal_load(src + 3);
    } else {
      if (c4 < DD)     v0 = src[0];
      if (c4 + 1 < DD) v1 = src[1];
      if (c4 + 2 < DD) v2 = src[2];
    }
    u16x4 o;
    o.x = f2bu(v0); o.y = f2bu(v1); o.z = f2bu(v2); o.w = f2bu(v3);
    u16x4* dst = (u16x4*)((unsigned short*)XBF + (size_t)row * KX + c4);
    __builtin_nontemporal_store(o, dst);
  }
}

// ---------------- layer-1: gate-major, in-register cell ----------------
// 256 blocks = 128 groups(8 sents) x 2 dirs, 640 threads (10 waves).
// Wave wv owns the {i,f,g,o} gate-quad of j-tile wv (j = wv*16 + c16).
// TB=4 steps per g: 2 pairs; rows 0-7 = even step sents, 8-15 = odd step.
// xs rows 360 bf16 (odd 16B-units), staged row-wise: 44 lanes x 16B = 704B/row,
// NT policy so streaming XBF doesn't evict L2-resident weights.
#define XS_SZ   23040u                    // bf16 [2p][16][360] = 2*16*720
#define HS_OFF  (2u * XS_SZ)              // = 46080; bf16 [16][168] = 5376
#define L1_SMEM (HS_OFF + 5376u)          // 51456 real
#define L1_SMEM_REQ 102400u               // padded: force 1 block/CU

template<bool BF>
__device__ __forceinline__ void stage_x(char* xsd, const float* __restrict__ x,
                                        const __hip_bfloat16* __restrict__ XBF,
                                        int t0, int dir, int s0, int tid, int lane, int wv)
{
  if constexpr (BF) {
    // 32 rows (2 tiles x 16), one gload_lds per row, lanes 0..43 active.
    #pragma unroll
    for (int i = 0; i < 4; ++i) {
      int rid = wv + i * 10;
      if (rid < 32 && lane < 44) {
        int p = rid >> 4, rr = rid & 15;
        int t = t0 + 2 * p + (rr >> 3);
        int s = s0 + (rr & 7);
        int tt = dir ? (127 - t) : t;
        const __hip_bfloat16* gp = XBF + ((size_t)s * TLEN + tt) * KX + lane * 8;
        gload_lds16_nt((const void*)gp, (void*)(xsd + rid * 720));
      }
    }
  } else {
    for (int e = tid; e < 2 * 16 * XR; e += 640) {
      int row16 = e / XR;
      int col = e - row16 * XR;
      int p = row16 >> 4, rr = row16 & 15;
      int t = t0 + 2 * p + (rr >> 3);
      int s = s0 + (rr & 7);
      int tt = dir ? (127 - t) : t;
      float v = (col < DD) ? x[((size_t)s * TLEN + tt) * DD + col] : 0.f;
      ((__hip_bfloat16*)xsd)[e] = __float2bfloat16(v);
    }
  }
}

template<bool BF>
__global__ __launch_bounds__(640)
void lstm1_kernel(
    const float* __restrict__ x, const __hip_bfloat16* __restrict__ XBF,
    const __hip_bfloat16* __restrict__ WXp, const __hip_bfloat16* __restrict__ WHp,
    const float* __restrict__ B1, float* __restrict__ SE)
{
  extern __shared__ char smem[];
  char* xs0 = smem;
  char* xs1 = smem + XS_SZ;
  __hip_bfloat16* hs = (__hip_bfloat16*)(smem + HS_OFF);

  const int tid = threadIdx.x;
  const int lane = tid & 63;
  const int wv = tid >> 6;            // 0..9 = j-tile
  const int dir = blockIdx.x & 1;
  const int s0 = (blockIdx.x >> 1) * 8;
  const int c16 = lane & 15;
  const int kgrp = lane >> 4;
  const int j = wv * 16 + c16;        // 0..159

  for (int e = tid; e < 16 * HR; e += 640) hs[e] = __float2bfloat16(0.f);

  float bias[4];
  #pragma unroll
  for (int g4 = 0; g4 < 4; ++g4) {
    bias[g4] = B1[dir * NP + g4 * 160 + j];
    asm volatile("" : "+v"(bias[g4]));
  }

  const __hip_bfloat16* WXd = WXp + (size_t)dir * KXP * NP * 8;
  const __hip_bfloat16* WHd = WHp + (size_t)dir * 20 * NP * 8;

  bf16x8 whr[5][4];
  #pragma unroll
  for (int kh = 0; kh < 5; ++kh)
    #pragma unroll
    for (int g4 = 0; g4 < 4; ++g4) {
      whr[kh][g4] = *reinterpret_cast<const bf16x8*>(
          WHd + ((size_t)(kh * 4 + kgrp) * NP + g4 * 160 + j) * 8);
      asm volatile("" : "+v"(whr[kh][g4]));
    }

  float creg[4] = {0.f, 0.f, 0.f, 0.f};
  float mxr[4] = {-3e38f, -3e38f, -3e38f, -3e38f};

  stage_x<BF>(xs0, x, XBF, 0, dir, s0, tid, lane, wv);
  bar_full();

  for (int g = 0; g < 32; ++g) {
    char* xsc = (g & 1) ? xs1 : xs0;
    char* xsn = (g & 1) ? xs0 : xs1;
    const __hip_bfloat16* xsb = (const __hip_bfloat16*)xsc;

    f32x4 acc[2][4];
    #pragma unroll
    for (int p = 0; p < 2; ++p)
      #pragma unroll
      for (int g4 = 0; g4 < 4; ++g4) acc[p][g4] = (f32x4){0.f, 0.f, 0.f, 0.f};

    // ---- phase A: x-projection for 4 steps (2 row-paired tiles) ----
    for (int kk = 0; kk < 11; ++kk) {
      bf16x8 a[2], b[4];
      #pragma unroll
      for (int p = 0; p < 2; ++p)
        a[p] = *reinterpret_cast<const bf16x8*>(xsb + (p * 16 + c16) * XR + kk * 32 + kgrp * 8);
      #pragma unroll
      for (int g4 = 0; g4 < 4; ++g4)
        b[g4] = *reinterpret_cast<const bf16x8*>(
            WXd + ((size_t)(kk * 4 + kgrp) * NP + g4 * 160 + j) * 8);
      #pragma unroll
      for (int p = 0; p < 2; ++p)
        #pragma unroll
        for (int g4 = 0; g4 < 4; ++g4)
          acc[p][g4] = MFMA_B16(a[p], b[g4], acc[p][g4]);
    }

    if (g < 31)
      stage_x<BF>(xsn, x, XBF, (g + 1) * 4, dir, s0, tid, lane, wv);

    // ---- phase B: 2 pairs = 4 recurrent steps ----
    #pragma unroll
    for (int p = 0; p < 2; ++p) {
      // MFMA1: rows 0-7 += h_prev_odd * Wh  (rows 8-15 see zeros)
      #pragma unroll
      for (int kh = 0; kh < 5; ++kh) {
        bf16x8 ah = *reinterpret_cast<const bf16x8*>(hs + c16 * HR + kh * 32 + kgrp * 8);
        #pragma unroll
        for (int g4 = 0; g4 < 4; ++g4)
          acc[p][g4] = MFMA_B16(ah, whr[kh][g4], acc[p][g4]);
      }
      // even-step cell: valid in kgrp<2 lanes (rows 0-7)
      {
        const bool act = (kgrp < 2);
        #pragma unroll
        for (int r = 0; r < 4; ++r) {
          float iv = sigm(acc[p][0][r] + bias[0]);
          float fv = sigm(acc[p][1][r] + bias[1]);
          float gv = tanh_fast(acc[p][2][r] + bias[2]);
          float ov = sigm(acc[p][3][r] + bias[3]);
          float cin = __shfl_xor(creg[r], 32);
          float cn = fv * cin + iv * gv;
          float h = ov * tanh_fast(cn);
          creg[r] = act ? cn : creg[r];
          mxr[r] = act ? fmaxf(mxr[r], h) : mxr[r];
          if (act) hs[(8 + kgrp * 4 + r) * HR + j] = __float2bfloat16(h);
        }
      }
      bar_lds();
      // MFMA2: rows 8-15 += h_even * Wh (rows 0-7 dead)
      #pragma unroll
      for (int kh = 0; kh < 5; ++kh) {
        bf16x8 ah = *reinterpret_cast<const bf16x8*>(hs + c16 * HR + kh * 32 + kgrp * 8);
        #pragma unroll
        for (int g4 = 0; g4 < 4; ++g4)
          acc[p][g4] = MFMA_B16(ah, whr[kh][g4], acc[p][g4]);
      }
      // odd-step cell: valid in kgrp>=2 lanes (rows 8-15)
      {
        const bool act = (kgrp >= 2);
        #pragma unroll
        for (int r = 0; r < 4; ++r) {
          float iv = sigm(acc[p][0][r] + bias[0]);
          float fv = sigm(acc[p][1][r] + bias[1]);
          float gv = tanh_fast(acc[p][2][r] + bias[2]);
          float ov = sigm(acc[p][3][r] + bias[3]);
          float cin = __shfl_xor(creg[r], 32);
          float cn = fv * cin + iv * gv;
          float h = ov * tanh_fast(cn);
          creg[r] = act ? cn : creg[r];
          mxr[r] = act ? fmaxf(mxr[r], h) : mxr[r];
          if (act) {
            int s = (kgrp - 2) * 4 + r;
            hs[s * HR + j] = __float2bfloat16(h);
            hs[(8 + s) * HR + j] = __float2bfloat16(0.f);
          }
        }
      }
      if (p == 1) bar_full(); else bar_lds();
    }
  }

  // SE: merge even/odd running max via shfl, write by kgrp<2 lanes
  #pragma unroll
  for (int r = 0; r < 4; ++r) {
    float m = fmaxf(mxr[r], __shfl_xor(mxr[r], 32));
    if (kgrp < 2 && j < HH)
      SE[(size_t)(s0 + kgrp * 4 + r) * 300 + dir * HH + j] = m;
  }
}

// ---------------- layer-2 input projection (gate-major output, zero pad) ----------------
__global__ __launch_bounds__(256, 1) void xg2_kernel(
    const float* __restrict__ SE, const float* __restrict__ W2I,
    const float* __restrict__ bif2, const float* __restrict__ bhf2,
    const float* __restrict__ bib2, const float* __restrict__ bhb2,
    float* __restrict__ XG2)
{
  __shared__ float se[32 * 304];
  const int d = blockIdx.x >> 5, st = blockIdx.x & 31, sb = st * 32;
  const int tid = threadIdx.x;
  for (int e = tid; e < 32 * 300; e += 256) {
    int si = e / 300, k = e - si * 300;
    se[si * 304 + k] = SE[(size_t)(sb + si) * 300 + k];
  }
  __syncthreads();
  for (int pass = 0; pass < 3; ++pass) {
    int n = pass * 256 + tid;
    if (n < GG) {
      int n2 = (n / 150) * 160 + (n % 150);
      float bias = d ? (bib2[n] + bhb2[n]) : (bif2[n] + bhf2[n]);
      float acc[32];
      #pragma unroll
      for (int si = 0; si < 32; ++si) acc[si] = bias;
      const float* wcol = W2I + (size_t)d * 300 * 608 + n;
      for (int k = 0; k < 300; ++k) {
        float wvv = wcol[(size_t)k * 608];
        #pragma unroll
        for (int si = 0; si < 32; ++si) acc[si] += wvv * se[si * 304 + k];
      }
      #pragma unroll
      for (int si = 0; si < 32; ++si)
        XG2[((size_t)d * NS + sb + si) * NG2 + n2] = acc[si];
    }
  }
  // zero the pad columns (j in [150,160) per gate)
  for (int e = tid; e < 32 * 40; e += 256) {
    int si = e / 40, q = e - si * 40;
    int g = q / 10, jp = 150 + (q - g * 10);
    XG2[((size_t)d * NS + sb + si) * NG2 + g * 160 + jp] = 0.f;
  }
}

// ---------------- layer-2 recurrence: gate-major MFMA, in-register cell ----------------
__global__ __launch_bounds__(640) void lstm2_kernel(
    const __hip_bfloat16* __restrict__ W2B, const float* __restrict__ XG2,
    float* __restrict__ H2O)
{
  const int dir = blockIdx.x;
  const int tid = threadIdx.x;
  const int lane = tid & 63;
  const int wv = tid >> 6;        // 0..9 = j-tile
  const int c16 = lane & 15;
  const int kg = lane >> 4;
  const int j = wv * 16 + c16;    // 0..159
  __shared__ __align__(16) __hip_bfloat16 hbuf[2][160];

  const f32x4 ZERO4 = {0.f, 0.f, 0.f, 0.f};

  const __hip_bfloat16* Wd = W2B + (size_t)dir * NP * 160;
  bf16x8 wf[5][4];
  #pragma unroll
  for (int kt = 0; kt < 5; ++kt)
    #pragma unroll
    for (int g4 = 0; g4 < 4; ++g4) {
      wf[kt][g4] = *reinterpret_cast<const bf16x8*>(
          Wd + (size_t)(g4 * 160 + j) * 160 + kt * 32 + kg * 8);
      asm volatile("" : "+v"(wf[kt][g4]));
    }

  if (tid < 160) hbuf[0][tid] = __float2bfloat16(0.f);
  __syncthreads();

  float creg = 0.f;
  const float* xg = XG2 + (size_t)dir * NS * NG2;
  float xv[4];
  {
    int ss0 = dir ? 1023 : 0;
    #pragma unroll
    for (int g4 = 0; g4 < 4; ++g4) xv[g4] = xg[(size_t)ss0 * NG2 + g4 * 160 + j];
  }

  for (int step = 0; step < 1024; ++step) {
    const int ss = dir ? (1023 - step) : step;
    float xn[4] = {0.f, 0.f, 0.f, 0.f};
    if (step < 1023) {
      int ss2 = dir ? (1022 - step) : (step + 1);
      #pragma unroll
      for (int g4 = 0; g4 < 4; ++g4) xn[g4] = xg[(size_t)ss2 * NG2 + g4 * 160 + j];
    }
    const int cur = step & 1;
    bf16x8 hf[5];
    #pragma unroll
    for (int kt = 0; kt < 5; ++kt)
      hf[kt] = *reinterpret_cast<const bf16x8*>(&hbuf[cur][kt * 32 + kg * 8]);
    f32x4 aA[4], aB[4];
    #pragma unroll
    for (int g4 = 0; g4 < 4; ++g4) {
      aA[g4] = MFMA_B16(hf[0], wf[0][g4], ZERO4);
      aB[g4] = MFMA_B16(hf[1], wf[1][g4], ZERO4);
    }
    #pragma unroll
    for (int g4 = 0; g4 < 4; ++g4) {
      aA[g4] = MFMA_B16(hf[2], wf[2][g4], aA[g4]);
      aB[g4] = MFMA_B16(hf[3], wf[3][g4], aB[g4]);
      aA[g4] = MFMA_B16(hf[4], wf[4][g4], aA[g4]);
    }
    float iv = sigm(aA[0][0] + aB[0][0] + xv[0]);
    float fv = sigm(aA[1][0] + aB[1][0] + xv[1]);
    float gv = tanh_fast(aA[2][0] + aB[2][0] + xv[2]);
    float ov = sigm(aA[3][0] + aB[3][0] + xv[3]);
    creg = fv * creg + iv * gv;
    float nh = ov * tanh_fast(creg);
    if (kg == 0) {
      hbuf[cur ^ 1][j] = __float2bfloat16(nh);
      if (j < HH) H2O[(size_t)ss * 300 + dir * HH + j] = nh;
    }
    bar_lds();
    #pragma unroll
    for (int g4 = 0; g4 < 4; ++g4) xv[g4] = xn[g4];
  }
}

// ---------------- head ----------------
__global__ __launch_bounds__(256, 1) void head_kernel(
    const float* __restrict__ H2O, const float* __restrict__ w_out,
    const float* __restrict__ b_out, float* __restrict__ out)
{
  int s = blockIdx.x * 256 + threadIdx.x;
  if (s >= NS) return;
  float acc[7];
  #pragma unroll
  for (int c = 0; c < 7; ++c) acc[c] = b_out[c];
  const float* hrow = H2O + (size_t)s * 300;
  for (int k = 0; k < 300; ++k) {
    float hv = hrow[k];
    #pragma unroll
    for (int c = 0; c < 7; ++c) acc[c] += hv * w_out[c * 300 + k];
  }
  float m = acc[0];
  #pragma unroll
  for (int c = 1; c < 7; ++c) m = fmaxf(m, acc[c]);
  float sum = 0.f;
  #pragma unroll
  for (int c = 0; c < 7; ++c) sum += __expf(acc[c] - m);
  float lse = m + __logf(sum);
  #pragma unroll
  for (int c = 0; c < 7; ++c) out[s * 7 + c] = acc[c] - lse;
}

extern "C" void kernel_launch(void* const* d_in, const int* in_sizes, int n_in,
                              void* d_out, int out_size, void* d_ws, size_t ws_size,
                              hipStream_t stream) {
  const float* x      = (const float*)d_in[0];
  const float* wif1   = (const float*)d_in[1];
  const float* whf1   = (const float*)d_in[2];
  const float* bif1   = (const float*)d_in[3];
  const float* bhf1   = (const float*)d_in[4];
  const float* wib1   = (const float*)d_in[5];
  const float* whb1   = (const float*)d_in[6];
  const float* bib1   = (const float*)d_in[7];
  const float* bhb1   = (const float*)d_in[8];
  const float* wif2   = (const float*)d_in[9];
  const float* whf2   = (const float*)d_in[10];
  const float* bif2   = (const float*)d_in[11];
  const float* bhf2   = (const float*)d_in[12];
  const float* wib2   = (const float*)d_in[13];
  const float* whb2   = (const float*)d_in[14];
  const float* bib2   = (const float*)d_in[15];
  const float* bhb2   = (const float*)d_in[16];
  const float* w_out  = (const float*)d_in[17];
  const float* b_out  = (const float*)d_in[18];

  char* ws = (char*)d_ws;
  __hip_bfloat16* WXp = (__hip_bfloat16*)(ws + OFF_WXP);
  __hip_bfloat16* WHp = (__hip_bfloat16*)(ws + OFF_WHP);
  float*    B1  = (float*)(ws + OFF_B1);
  __hip_bfloat16* W2B = (__hip_bfloat16*)(ws + OFF_W2B);
  float*    W2I = (float*)(ws + OFF_W2I);
  float*    SE  = (float*)(ws + OFF_SE);
  float*    XG2 = (float*)(ws + OFF_XG2);
  float*    H2O = (float*)(ws + OFF_H2O);
  __hip_bfloat16* XBF = (__hip_bfloat16*)(ws + OFF_XBF);

  const bool useBF = (ws_size >= NEED_BF);

  prep_kernel<<<(PE4 + 255) / 256, 256, 0, stream>>>(
      wif1, whf1, bif1, bhf1, wib1, whb1, bib1, bhb1,
      wif2, wib2, whf2, whb2, WXp, WHp, B1, W2B, W2I);

  if (useBF)
    xcvt_kernel<<<4096, 256, 0, stream>>>(x, XBF);

  (void)hipFuncSetAttribute((const void*)(lstm1_kernel<true>),
                            hipFuncAttributeMaxDynamicSharedMemorySize, L1_SMEM_REQ);
  (void)hipFuncSetAttribute((const void*)(lstm1_kernel<false>),
                            hipFuncAttributeMaxDynamicSharedMemorySize, L1_SMEM_REQ);

  if (useBF)
    lstm1_kernel<true><<<256, 640, L1_SMEM_REQ, stream>>>(x, XBF, WXp, WHp, B1, SE);
  else
    lstm1_kernel<false><<<256, 640, L1_SMEM_REQ, stream>>>(x, XBF, WXp, WHp, B1, SE);

  xg2_kernel<<<64, 256, 0, stream>>>(SE, W2I, bif2, bhf2, bib2, bhb2, XG2);

  lstm2_kernel<<<2, 640, 0, stream>>>(W2B, XG2, H2O);

  head_kernel<<<4, 256, 0, stream>>>(H2O, w_out, b_out, (float*)d_out);
}

// Round 12
// 1604.058 us; speedup vs baseline: 1.0757x; 1.0714x over previous
//
#include <hip/hip_runtime.h>
#include <hip/hip_bf16.h>
#include <hip/hip_fp16.h>

typedef short bf16x8 __attribute__((ext_vector_type(8)));
typedef float f32x4 __attribute__((ext_vector_type(4)));
typedef unsigned short u16x4 __attribute__((ext_vector_type(4)));
typedef unsigned int uint32;

#define MFMA_B16(a,b,c) __builtin_amdgcn_mfma_f32_16x16x32_bf16(a,b,c,0,0,0)

// ---------------- geometry ----------------
#define NS   1024
#define TLEN 128
#define DD   343
#define HH   150
#define GG   600
#define KX   352    // XBF row width (global)
#define XR   360    // xs LDS row width (720B = 45x16B odd)
#define HR   168    // hs LDS row width (336B = 21x16B odd)
#define KXP  44
#define NP   640    // gate-major padded dim: n' = gate*160 + j, j<160
#define NG2  640    // XG2 row width (gate-major)

// ---------------- ws layout (bytes) ----------------
#define OFF_WXP  0u          // bf16 [2][44][640][8]   901120
#define OFF_WHP  901120u     // bf16 [2][20][640][8]   409600
#define OFF_B1   1310720u    // f32  [2][640]          5120
#define OFF_W2B  1315840u    // bf16 [2][640][160]     409600
#define OFF_W2I  1725440u    // f32  [2][300][608]     1459200
#define OFF_SE   3184640u    // f32  [1024][300]       1228800
#define OFF_XG2  4413440u    // f32  [2][1024][640]    5242880
#define OFF_H2O  9656320u    // f32  [1024][300]       1228800
#define OFF_XBF  10885120u   // bf16 [1024][128][352]  92274688
#define NEED_BF  103159808ull

// prep section boundaries (element counts)
#define PE0 450560            // WXp
#define PE1 655360            // + WHp 204800
#define PE2 656640            // + B1 1280
#define PE3 861440            // + W2B 204800
#define PE4 1226240           // + W2I 364800

__device__ __forceinline__ float rcp_fast(float x) { return __builtin_amdgcn_rcpf(x); }
__device__ __forceinline__ float sigm(float x) { return rcp_fast(1.f + __expf(-x)); }
__device__ __forceinline__ float tanh_fast(float x) { return 1.f - 2.f * rcp_fast(__expf(2.f * x) + 1.f); }

typedef __attribute__((address_space(1))) const void GASV;
typedef __attribute__((address_space(3))) void LASV;
__device__ __forceinline__ void gload_lds16(const void* g, void* l) {
  __builtin_amdgcn_global_load_lds((GASV*)g, (LASV*)l, 16, 0, 0);
}

__device__ __forceinline__ void bar_lds() {
  asm volatile("s_waitcnt lgkmcnt(0)" ::: "memory");
  __builtin_amdgcn_s_barrier();
  asm volatile("" ::: "memory");
}
__device__ __forceinline__ void bar_full() {
  asm volatile("s_waitcnt vmcnt(0) lgkmcnt(0)" ::: "memory");
  __builtin_amdgcn_s_barrier();
  asm volatile("" ::: "memory");
}

__device__ __forceinline__ unsigned short f2bu(float v) {
  __hip_bfloat16 b = __float2bfloat16(v);
  return __builtin_bit_cast(unsigned short, b);
}

// ---------------- prep: pack weights gate-major (n' = g*160 + j) ----------------
__global__ __launch_bounds__(256) void prep_kernel(
    const float* __restrict__ wif1, const float* __restrict__ whf1,
    const float* __restrict__ bif1, const float* __restrict__ bhf1,
    const float* __restrict__ wib1, const float* __restrict__ whb1,
    const float* __restrict__ bib1, const float* __restrict__ bhb1,
    const float* __restrict__ wif2, const float* __restrict__ wib2,
    const float* __restrict__ whf2, const float* __restrict__ whb2,
    __hip_bfloat16* __restrict__ WXp, __hip_bfloat16* __restrict__ WHp,
    float* __restrict__ B1, __hip_bfloat16* __restrict__ W2B, float* __restrict__ W2I)
{
  int i = blockIdx.x * 256 + threadIdx.x;
  if (i < PE0) {
    int d = i / 225280; int r = i - d * 225280;
    int p = r / 5120;   int r2 = r - p * 5120;
    int n2 = r2 >> 3;   int jj = r2 & 7;
    int k = p * 8 + jj;
    int g = n2 / 160, j = n2 - g * 160;
    const float* w = d ? wib1 : wif1;
    float v = (j < HH && k < DD) ? w[(g * HH + j) * DD + k] : 0.f;
    WXp[i] = __float2bfloat16(v);
  } else if (i < PE1) {
    int ii = i - PE0;
    int d = ii / 102400; int r = ii - d * 102400;
    int p = r / 5120;    int r2 = r - p * 5120;
    int n2 = r2 >> 3;    int jj = r2 & 7;
    int k = p * 8 + jj;
    int g = n2 / 160, j = n2 - g * 160;
    const float* w = d ? whb1 : whf1;
    float v = (j < HH && k < HH) ? w[(g * HH + j) * HH + k] : 0.f;
    WHp[ii] = __float2bfloat16(v);
  } else if (i < PE2) {
    int ii = i - PE1;
    int d = ii / NP; int n2 = ii - d * NP;
    int g = n2 / 160, j = n2 - g * 160;
    float v = 0.f;
    if (j < HH) {
      int n = g * HH + j;
      v = d ? (bib1[n] + bhb1[n]) : (bif1[n] + bhf1[n]);
    }
    B1[ii] = v;
  } else if (i < PE3) {
    int ii = i - PE2;
    int d = ii / 102400; int r = ii - d * 102400;
    int n2 = r / 160;    int k = r - n2 * 160;
    int g = n2 / 160, j = n2 - g * 160;
    const float* w = d ? whb2 : whf2;
    float v = (j < HH && k < HH) ? w[(g * HH + j) * HH + k] : 0.f;
    W2B[ii] = __float2bfloat16(v);
  } else if (i < PE4) {
    int ii = i - PE3;
    int d = ii / 182400; int r = ii - d * 182400;
    int k = r / 608;     int n = r - k * 608;
    const float* w = d ? wib2 : wif2;
    float v = (n < GG) ? w[n * 300 + k] : 0.f;
    W2I[ii] = v;
  }
}

// ---------------- x -> bf16 padded [S][T][352] ----------------
__global__ __launch_bounds__(256) void xcvt_kernel(
    const float* __restrict__ x, __hip_bfloat16* __restrict__ XBF)
{
  const int total4 = NS * TLEN * (KX / 4);
  for (int idx = blockIdx.x * 256 + threadIdx.x; idx < total4; idx += gridDim.x * 256) {
    int row = idx / 88;
    int c4 = (idx - row * 88) * 4;
    const float* src = x + (size_t)row * DD + c4;
    float v0 = 0.f, v1 = 0.f, v2 = 0.f, v3 = 0.f;
    if (c4 + 3 < DD) {
      v0 = __builtin_nontemporal_load(src);
      v1 = __builtin_nontemporal_load(src + 1);
      v2 = __builtin_nontemporal_load(src + 2);
      v3 = __builtin_nontemporal_load(src + 3);
    } else {
      if (c4 < DD)     v0 = src[0];
      if (c4 + 1 < DD) v1 = src[1];
      if (c4 + 2 < DD) v2 = src[2];
    }
    u16x4 o;
    o.x = f2bu(v0); o.y = f2bu(v1); o.z = f2bu(v2); o.w = f2bu(v3);
    u16x4* dst = (u16x4*)((unsigned short*)XBF + (size_t)row * KX + c4);
    __builtin_nontemporal_store(o, dst);
  }
}

// ---------------- layer-1: gate-major, in-register cell, TB=8 ----------------
// 256 blocks = 128 groups(8 sents) x 2 dirs, 640 threads (10 waves).
// Wave wv owns the {i,f,g,o} gate-quad of j-tile wv (j = wv*16 + c16).
// TB=8 steps per g: 4 pairs; tile p rows 0-7 = step 2p (8 sents), 8-15 = step 2p+1.
// Weight slice (450KB) re-read once per g-iter: TB=8 halves that traffic vs TB=4
// (round-11 PMC: FETCH 2GB = weight L2-misses dominated; purely fetch-bound).
#define XS_SZ   46080u                    // bf16 [4 tiles][16][360] = 4*16*720
#define HS_OFF  (2u * XS_SZ)              // = 92160; bf16 [16][168] = 5376
#define L1_SMEM (HS_OFF + 5376u)          // 97536 -> 1 block/CU naturally

template<bool BF>
__device__ __forceinline__ void stage_x(char* xsd, const float* __restrict__ x,
                                        const __hip_bfloat16* __restrict__ XBF,
                                        int t0, int dir, int s0, int tid, int lane, int wv)
{
  if constexpr (BF) {
    // 64 rows (4 tiles x 16), one gload_lds per row, lanes 0..43 active (704B).
    #pragma unroll
    for (int i = 0; i < 7; ++i) {
      int rid = wv + i * 10;
      if (rid < 64 && lane < 44) {
        int p = rid >> 4, rr = rid & 15;
        int t = t0 + 2 * p + (rr >> 3);
        int s = s0 + (rr & 7);
        int tt = dir ? (127 - t) : t;
        const __hip_bfloat16* gp = XBF + ((size_t)s * TLEN + tt) * KX + lane * 8;
        gload_lds16((const void*)gp, (void*)(xsd + rid * 720));
      }
    }
  } else {
    for (int e = tid; e < 4 * 16 * XR; e += 640) {
      int row16 = e / XR;
      int col = e - row16 * XR;
      int p = row16 >> 4, rr = row16 & 15;
      int t = t0 + 2 * p + (rr >> 3);
      int s = s0 + (rr & 7);
      int tt = dir ? (127 - t) : t;
      float v = (col < DD) ? x[((size_t)s * TLEN + tt) * DD + col] : 0.f;
      ((__hip_bfloat16*)xsd)[e] = __float2bfloat16(v);
    }
  }
}

template<bool BF>
__global__ __launch_bounds__(640)
void lstm1_kernel(
    const float* __restrict__ x, const __hip_bfloat16* __restrict__ XBF,
    const __hip_bfloat16* __restrict__ WXp, const __hip_bfloat16* __restrict__ WHp,
    const float* __restrict__ B1, float* __restrict__ SE)
{
  extern __shared__ char smem[];
  char* xs0 = smem;
  char* xs1 = smem + XS_SZ;
  __hip_bfloat16* hs = (__hip_bfloat16*)(smem + HS_OFF);

  const int tid = threadIdx.x;
  const int lane = tid & 63;
  const int wv = tid >> 6;            // 0..9 = j-tile
  const int dir = blockIdx.x & 1;
  const int s0 = (blockIdx.x >> 1) * 8;
  const int c16 = lane & 15;
  const int kgrp = lane >> 4;
  const int j = wv * 16 + c16;        // 0..159

  for (int e = tid; e < 16 * HR; e += 640) hs[e] = __float2bfloat16(0.f);

  float bias[4];
  #pragma unroll
  for (int g4 = 0; g4 < 4; ++g4) {
    bias[g4] = B1[dir * NP + g4 * 160 + j];
    asm volatile("" : "+v"(bias[g4]));
  }

  const __hip_bfloat16* WXd = WXp + (size_t)dir * KXP * NP * 8;
  const __hip_bfloat16* WHd = WHp + (size_t)dir * 20 * NP * 8;

  bf16x8 whr[5][4];
  #pragma unroll
  for (int kh = 0; kh < 5; ++kh)
    #pragma unroll
    for (int g4 = 0; g4 < 4; ++g4) {
      whr[kh][g4] = *reinterpret_cast<const bf16x8*>(
          WHd + ((size_t)(kh * 4 + kgrp) * NP + g4 * 160 + j) * 8);
      asm volatile("" : "+v"(whr[kh][g4]));
    }

  float creg[4] = {0.f, 0.f, 0.f, 0.f};
  float mxr[4] = {-3e38f, -3e38f, -3e38f, -3e38f};

  stage_x<BF>(xs0, x, XBF, 0, dir, s0, tid, lane, wv);
  bar_full();

  for (int g = 0; g < 16; ++g) {
    char* xsc = (g & 1) ? xs1 : xs0;
    char* xsn = (g & 1) ? xs0 : xs1;
    const __hip_bfloat16* xsb = (const __hip_bfloat16*)xsc;

    f32x4 acc[4][4];
    #pragma unroll
    for (int p = 0; p < 4; ++p)
      #pragma unroll
      for (int g4 = 0; g4 < 4; ++g4) acc[p][g4] = (f32x4){0.f, 0.f, 0.f, 0.f};

    // ---- phase A: x-projection for 8 steps (4 row-paired tiles) ----
    for (int kk = 0; kk < 11; ++kk) {
      bf16x8 a[4], b[4];
      #pragma unroll
      for (int p = 0; p < 4; ++p)
        a[p] = *reinterpret_cast<const bf16x8*>(xsb + (p * 16 + c16) * XR + kk * 32 + kgrp * 8);
      #pragma unroll
      for (int g4 = 0; g4 < 4; ++g4)
        b[g4] = *reinterpret_cast<const bf16x8*>(
            WXd + ((size_t)(kk * 4 + kgrp) * NP + g4 * 160 + j) * 8);
      #pragma unroll
      for (int p = 0; p < 4; ++p)
        #pragma unroll
        for (int g4 = 0; g4 < 4; ++g4)
          acc[p][g4] = MFMA_B16(a[p], b[g4], acc[p][g4]);
    }

    if (g < 15)
      stage_x<BF>(xsn, x, XBF, (g + 1) * 8, dir, s0, tid, lane, wv);

    // ---- phase B: 4 pairs = 8 recurrent steps ----
    #pragma unroll
    for (int p = 0; p < 4; ++p) {
      // MFMA1: rows 0-7 += h_prev_odd * Wh  (rows 8-15 see zeros)
      #pragma unroll
      for (int kh = 0; kh < 5; ++kh) {
        bf16x8 ah = *reinterpret_cast<const bf16x8*>(hs + c16 * HR + kh * 32 + kgrp * 8);
        #pragma unroll
        for (int g4 = 0; g4 < 4; ++g4)
          acc[p][g4] = MFMA_B16(ah, whr[kh][g4], acc[p][g4]);
      }
      // even-step cell: valid in kgrp<2 lanes (rows 0-7)
      {
        const bool act = (kgrp < 2);
        #pragma unroll
        for (int r = 0; r < 4; ++r) {
          float iv = sigm(acc[p][0][r] + bias[0]);
          float fv = sigm(acc[p][1][r] + bias[1]);
          float gv = tanh_fast(acc[p][2][r] + bias[2]);
          float ov = sigm(acc[p][3][r] + bias[3]);
          float cin = __shfl_xor(creg[r], 32);
          float cn = fv * cin + iv * gv;
          float h = ov * tanh_fast(cn);
          creg[r] = act ? cn : creg[r];
          mxr[r] = act ? fmaxf(mxr[r], h) : mxr[r];
          if (act) hs[(8 + kgrp * 4 + r) * HR + j] = __float2bfloat16(h);
        }
      }
      bar_lds();
      // MFMA2: rows 8-15 += h_even * Wh (rows 0-7 dead)
      #pragma unroll
      for (int kh = 0; kh < 5; ++kh) {
        bf16x8 ah = *reinterpret_cast<const bf16x8*>(hs + c16 * HR + kh * 32 + kgrp * 8);
        #pragma unroll
        for (int g4 = 0; g4 < 4; ++g4)
          acc[p][g4] = MFMA_B16(ah, whr[kh][g4], acc[p][g4]);
      }
      // odd-step cell: valid in kgrp>=2 lanes (rows 8-15)
      {
        const bool act = (kgrp >= 2);
        #pragma unroll
        for (int r = 0; r < 4; ++r) {
          float iv = sigm(acc[p][0][r] + bias[0]);
          float fv = sigm(acc[p][1][r] + bias[1]);
          float gv = tanh_fast(acc[p][2][r] + bias[2]);
          float ov = sigm(acc[p][3][r] + bias[3]);
          float cin = __shfl_xor(creg[r], 32);
          float cn = fv * cin + iv * gv;
          float h = ov * tanh_fast(cn);
          creg[r] = act ? cn : creg[r];
          mxr[r] = act ? fmaxf(mxr[r], h) : mxr[r];
          if (act) {
            int s = (kgrp - 2) * 4 + r;
            hs[s * HR + j] = __float2bfloat16(h);
            hs[(8 + s) * HR + j] = __float2bfloat16(0.f);
          }
        }
      }
      if (p == 3) bar_full(); else bar_lds();
    }
  }

  // SE: merge even/odd running max via shfl, write by kgrp<2 lanes
  #pragma unroll
  for (int r = 0; r < 4; ++r) {
    float m = fmaxf(mxr[r], __shfl_xor(mxr[r], 32));
    if (kgrp < 2 && j < HH)
      SE[(size_t)(s0 + kgrp * 4 + r) * 300 + dir * HH + j] = m;
  }
}

// ---------------- layer-2 input projection (gate-major output, zero pad) ----------------
__global__ __launch_bounds__(256, 1) void xg2_kernel(
    const float* __restrict__ SE, const float* __restrict__ W2I,
    const float* __restrict__ bif2, const float* __restrict__ bhf2,
    const float* __restrict__ bib2, const float* __restrict__ bhb2,
    float* __restrict__ XG2)
{
  __shared__ float se[32 * 304];
  const int d = blockIdx.x >> 5, st = blockIdx.x & 31, sb = st * 32;
  const int tid = threadIdx.x;
  for (int e = tid; e < 32 * 300; e += 256) {
    int si = e / 300, k = e - si * 300;
    se[si * 304 + k] = SE[(size_t)(sb + si) * 300 + k];
  }
  __syncthreads();
  for (int pass = 0; pass < 3; ++pass) {
    int n = pass * 256 + tid;
    if (n < GG) {
      int n2 = (n / 150) * 160 + (n % 150);
      float bias = d ? (bib2[n] + bhb2[n]) : (bif2[n] + bhf2[n]);
      float acc[32];
      #pragma unroll
      for (int si = 0; si < 32; ++si) acc[si] = bias;
      const float* wcol = W2I + (size_t)d * 300 * 608 + n;
      for (int k = 0; k < 300; ++k) {
        float wvv = wcol[(size_t)k * 608];
        #pragma unroll
        for (int si = 0; si < 32; ++si) acc[si] += wvv * se[si * 304 + k];
      }
      #pragma unroll
      for (int si = 0; si < 32; ++si)
        XG2[((size_t)d * NS + sb + si) * NG2 + n2] = acc[si];
    }
  }
  // zero the pad columns (j in [150,160) per gate)
  for (int e = tid; e < 32 * 40; e += 256) {
    int si = e / 40, q = e - si * 40;
    int g = q / 10, jp = 150 + (q - g * 10);
    XG2[((size_t)d * NS + sb + si) * NG2 + g * 160 + jp] = 0.f;
  }
}

// ---------------- layer-2 recurrence: gate-major MFMA, in-register cell ----------------
__global__ __launch_bounds__(640) void lstm2_kernel(
    const __hip_bfloat16* __restrict__ W2B, const float* __restrict__ XG2,
    float* __restrict__ H2O)
{
  const int dir = blockIdx.x;
  const int tid = threadIdx.x;
  const int lane = tid & 63;
  const int wv = tid >> 6;        // 0..9 = j-tile
  const int c16 = lane & 15;
  const int kg = lane >> 4;
  const int j = wv * 16 + c16;    // 0..159
  __shared__ __align__(16) __hip_bfloat16 hbuf[2][160];

  const f32x4 ZERO4 = {0.f, 0.f, 0.f, 0.f};

  const __hip_bfloat16* Wd = W2B + (size_t)dir * NP * 160;
  bf16x8 wf[5][4];
  #pragma unroll
  for (int kt = 0; kt < 5; ++kt)
    #pragma unroll
    for (int g4 = 0; g4 < 4; ++g4) {
      wf[kt][g4] = *reinterpret_cast<const bf16x8*>(
          Wd + (size_t)(g4 * 160 + j) * 160 + kt * 32 + kg * 8);
      asm volatile("" : "+v"(wf[kt][g4]));
    }

  if (tid < 160) hbuf[0][tid] = __float2bfloat16(0.f);
  __syncthreads();

  float creg = 0.f;
  const float* xg = XG2 + (size_t)dir * NS * NG2;
  float xv[4];
  {
    int ss0 = dir ? 1023 : 0;
    #pragma unroll
    for (int g4 = 0; g4 < 4; ++g4) xv[g4] = xg[(size_t)ss0 * NG2 + g4 * 160 + j];
  }

  for (int step = 0; step < 1024; ++step) {
    const int ss = dir ? (1023 - step) : step;
    float xn[4] = {0.f, 0.f, 0.f, 0.f};
    if (step < 1023) {
      int ss2 = dir ? (1022 - step) : (step + 1);
      #pragma unroll
      for (int g4 = 0; g4 < 4; ++g4) xn[g4] = xg[(size_t)ss2 * NG2 + g4 * 160 + j];
    }
    const int cur = step & 1;
    bf16x8 hf[5];
    #pragma unroll
    for (int kt = 0; kt < 5; ++kt)
      hf[kt] = *reinterpret_cast<const bf16x8*>(&hbuf[cur][kt * 32 + kg * 8]);
    f32x4 aA[4], aB[4];
    #pragma unroll
    for (int g4 = 0; g4 < 4; ++g4) {
      aA[g4] = MFMA_B16(hf[0], wf[0][g4], ZERO4);
      aB[g4] = MFMA_B16(hf[1], wf[1][g4], ZERO4);
    }
    #pragma unroll
    for (int g4 = 0; g4 < 4; ++g4) {
      aA[g4] = MFMA_B16(hf[2], wf[2][g4], aA[g4]);
      aB[g4] = MFMA_B16(hf[3], wf[3][g4], aB[g4]);
      aA[g4] = MFMA_B16(hf[4], wf[4][g4], aA[g4]);
    }
    float iv = sigm(aA[0][0] + aB[0][0] + xv[0]);
    float fv = sigm(aA[1][0] + aB[1][0] + xv[1]);
    float gv = tanh_fast(aA[2][0] + aB[2][0] + xv[2]);
    float ov = sigm(aA[3][0] + aB[3][0] + xv[3]);
    creg = fv * creg + iv * gv;
    float nh = ov * tanh_fast(creg);
    if (kg == 0) {
      hbuf[cur ^ 1][j] = __float2bfloat16(nh);
      if (j < HH) H2O[(size_t)ss * 300 + dir * HH + j] = nh;
    }
    bar_lds();
    #pragma unroll
    for (int g4 = 0; g4 < 4; ++g4) xv[g4] = xn[g4];
  }
}

// ---------------- head ----------------
__global__ __launch_bounds__(256, 1) void head_kernel(
    const float* __restrict__ H2O, const float* __restrict__ w_out,
    const float* __restrict__ b_out, float* __restrict__ out)
{
  int s = blockIdx.x * 256 + threadIdx.x;
  if (s >= NS) return;
  float acc[7];
  #pragma unroll
  for (int c = 0; c < 7; ++c) acc[c] = b_out[c];
  const float* hrow = H2O + (size_t)s * 300;
  for (int k = 0; k < 300; ++k) {
    float hv = hrow[k];
    #pragma unroll
    for (int c = 0; c < 7; ++c) acc[c] += hv * w_out[c * 300 + k];
  }
  float m = acc[0];
  #pragma unroll
  for (int c = 1; c < 7; ++c) m = fmaxf(m, acc[c]);
  float sum = 0.f;
  #pragma unroll
  for (int c = 0; c < 7; ++c) sum += __expf(acc[c] - m);
  float lse = m + __logf(sum);
  #pragma unroll
  for (int c = 0; c < 7; ++c) out[s * 7 + c] = acc[c] - lse;
}

extern "C" void kernel_launch(void* const* d_in, const int* in_sizes, int n_in,
                              void* d_out, int out_size, void* d_ws, size_t ws_size,
                              hipStream_t stream) {
  const float* x      = (const float*)d_in[0];
  const float* wif1   = (const float*)d_in[1];
  const float* whf1   = (const float*)d_in[2];
  const float* bif1   = (const float*)d_in[3];
  const float* bhf1   = (const float*)d_in[4];
  const float* wib1   = (const float*)d_in[5];
  const float* whb1   = (const float*)d_in[6];
  const float* bib1   = (const float*)d_in[7];
  const float* bhb1   = (const float*)d_in[8];
  const float* wif2   = (const float*)d_in[9];
  const float* whf2   = (const float*)d_in[10];
  const float* bif2   = (const float*)d_in[11];
  const float* bhf2   = (const float*)d_in[12];
  const float* wib2   = (const float*)d_in[13];
  const float* whb2   = (const float*)d_in[14];
  const float* bib2   = (const float*)d_in[15];
  const float* bhb2   = (const float*)d_in[16];
  const float* w_out  = (const float*)d_in[17];
  const float* b_out  = (const float*)d_in[18];

  char* ws = (char*)d_ws;
  __hip_bfloat16* WXp = (__hip_bfloat16*)(ws + OFF_WXP);
  __hip_bfloat16* WHp = (__hip_bfloat16*)(ws + OFF_WHP);
  float*    B1  = (float*)(ws + OFF_B1);
  __hip_bfloat16* W2B = (__hip_bfloat16*)(ws + OFF_W2B);
  float*    W2I = (float*)(ws + OFF_W2I);
  float*    SE  = (float*)(ws + OFF_SE);
  float*    XG2 = (float*)(ws + OFF_XG2);
  float*    H2O = (float*)(ws + OFF_H2O);
  __hip_bfloat16* XBF = (__hip_bfloat16*)(ws + OFF_XBF);

  const bool useBF = (ws_size >= NEED_BF);

  prep_kernel<<<(PE4 + 255) / 256, 256, 0, stream>>>(
      wif1, whf1, bif1, bhf1, wib1, whb1, bib1, bhb1,
      wif2, wib2, whf2, whb2, WXp, WHp, B1, W2B, W2I);

  if (useBF)
    xcvt_kernel<<<4096, 256, 0, stream>>>(x, XBF);

  (void)hipFuncSetAttribute((const void*)(lstm1_kernel<true>),
                            hipFuncAttributeMaxDynamicSharedMemorySize, L1_SMEM);
  (void)hipFuncSetAttribute((const void*)(lstm1_kernel<false>),
                            hipFuncAttributeMaxDynamicSharedMemorySize, L1_SMEM);

  if (useBF)
    lstm1_kernel<true><<<256, 640, L1_SMEM, stream>>>(x, XBF, WXp, WHp, B1, SE);
  else
    lstm1_kernel<false><<<256, 640, L1_SMEM, stream>>>(x, XBF, WXp, WHp, B1, SE);

  xg2_kernel<<<64, 256, 0, stream>>>(SE, W2I, bif2, bhf2, bib2, bhb2, XG2);

  lstm2_kernel<<<2, 640, 0, stream>>>(W2B, XG2, H2O);

  head_kernel<<<4, 256, 0, stream>>>(H2O, w_out, b_out, (float*)d_out);
}